// Round 12
// baseline (3256.684 us; speedup 1.0000x reference)
//
#include <hip/hip_runtime.h>
#include <hip/hip_bf16.h>

// FP8Linear: out = Xq @ Wq^T + bias. Reference quantize (scale=1) == RNE
// conversion to OCP e4m3fn; x stored as e4m3(x); w stored as e4m3(w*2^6)
// with MFMA B-scale 2^-6 (e8m0 0x79) so all |w|>=2^-12 quantize EXACTLY.
// GEMM R12: R11 base (256x256, BK=128, 8 waves 2Mx4N, 2x64KB LDS dbuf,
// mfma_scale_f32_32x32x64_f8f6f4) + true 8-phase/2-K-tile counted-vmcnt
// schedule (T3+T4+T5). Key implementation rules (R3/R7 post-mortems):
// waits are BARE asm (no "memory" clobber -> no compiler pre-drain),
// NO sched_barrier (m141: order-pinning regression), plain-C ds_reads
// (compiler inserts its own precise lgkmcnt). vmcnt(4) at P4/P8 only;
// every staged half-matrix has >=2 phases issue->drain cover; buffers
// fixed even(X)/odd(Y); staging slots at region-retirement points.

typedef int i32x4 __attribute__((ext_vector_type(4)));
typedef int i32x8 __attribute__((ext_vector_type(8)));
typedef float f32x16 __attribute__((ext_vector_type(16)));

#define BM 256
#define BN 256
#define BK 128

// clip to +-448, scale (1 or 64), RNE-encode 8 f32 -> 8 e4m3 bytes.
__global__ __launch_bounds__(256) void quant8(
    const float4* __restrict__ in, int2* __restrict__ out, int n8, float scale) {
    int i = blockIdx.x * blockDim.x + threadIdx.x;
    if (i >= n8) return;
    float4 a = in[i * 2];
    float4 b = in[i * 2 + 1];
    float c0 = fminf(fmaxf(a.x, -448.f), 448.f) * scale;
    float c1 = fminf(fmaxf(a.y, -448.f), 448.f) * scale;
    float c2 = fminf(fmaxf(a.z, -448.f), 448.f) * scale;
    float c3 = fminf(fmaxf(a.w, -448.f), 448.f) * scale;
    float c4 = fminf(fmaxf(b.x, -448.f), 448.f) * scale;
    float c5 = fminf(fmaxf(b.y, -448.f), 448.f) * scale;
    float c6 = fminf(fmaxf(b.z, -448.f), 448.f) * scale;
    float c7 = fminf(fmaxf(b.w, -448.f), 448.f) * scale;
    int lo = __builtin_amdgcn_cvt_pk_fp8_f32(c0, c1, 0, false);
    lo = __builtin_amdgcn_cvt_pk_fp8_f32(c2, c3, lo, true);
    int hi = __builtin_amdgcn_cvt_pk_fp8_f32(c4, c5, 0, false);
    hi = __builtin_amdgcn_cvt_pk_fp8_f32(c6, c7, hi, true);
    out[i] = make_int2(lo, hi);
}

__device__ __forceinline__ void gload_lds16(const void* g, void* l) {
    __builtin_amdgcn_global_load_lds(
        (const __attribute__((address_space(1))) void*)g,
        (__attribute__((address_space(3))) void*)l,
        16, 0, 0);
}

// Read one lane's 32-byte k-block (logical byte cols [c0, c0+32)) of `row`
// from a swizzled [rows][128B] LDS tile. LDS[r][c] holds G[r][c ^ sw(r)],
// sw(r) = (r&7)<<4, so logical col cl lives at LDS col cl ^ sw(r).
__device__ __forceinline__ i32x8 frag32(const unsigned char* base, int row, int c0) {
    const int sw = (row & 7) << 4;
    const unsigned char* p = base + row * 128;
    i32x4 lo = *(const i32x4*)(p + (c0 ^ sw));
    i32x4 hi = *(const i32x4*)(p + ((c0 + 16) ^ sw));
    i32x8 r;
    r[0] = lo[0]; r[1] = lo[1]; r[2] = lo[2]; r[3] = lo[3];
    r[4] = hi[0]; r[5] = hi[1]; r[6] = hi[2]; r[7] = hi[3];
    return r;
}

// A: Xq8 [M][K] e4m3, B: Wq8 [N][K] e4m3 (pre-scaled by 2^6), C: [M][N] f32
__global__ __launch_bounds__(512, 1) void gemm_fp8(
    const unsigned char* __restrict__ A, const unsigned char* __restrict__ B,
    const float* __restrict__ bias, float* __restrict__ C,
    int M, int N, int K) {
    extern __shared__ unsigned char lds[];
    unsigned char* const XA = lds;            // even tiles
    unsigned char* const XB = lds + 32768;
    unsigned char* const YA = lds + 65536;    // odd tiles
    unsigned char* const YB = lds + 98304;

    const int tid = threadIdx.x;
    const int lane = tid & 63;
    const int wave = tid >> 6;
    const int wr = wave >> 2;   // 0..1 -> 128 A-rows each
    const int wc = wave & 3;    // 0..3 -> 64 B-cols each

    // XCD-aware bijective block swizzle (nwg % 8 == 0)
    const int nwg = gridDim.x;
    const int per = nwg >> 3;
    const int bid = blockIdx.x;
    const int wg = (bid & 7) * per + (bid >> 3);
    const int mtiles = M / BM;
    const int bm = wg % mtiles;
    const int bn = wg / mtiles;

    const int arow0 = bm * BM, bcol0 = bn * BN;
    const int NT = K / BK;  // 32 (even)

    const int rl = lane & 31;    // fragment row-within-32 (A row / B col)
    const int g2 = lane >> 5;    // k-half selector within 64-byte mfma k-range

    const unsigned char* const Ag = A + (size_t)arow0 * K;
    const unsigned char* const Bg = B + (size_t)bcol0 * K;

    // staging: half-matrix (128 rows x 128B = 16KB) = 2 gload instrs/thread.
    // LDS dest linear (DMA constraint), global source pre-swizzled.
    const int srow = tid >> 3;                       // 0..63
    const int ssrc_col = ((tid & 7) * 16) ^ (((tid >> 3) & 7) << 4);
    const int sdst = tid * 16;

    auto stageh = [&](const unsigned char* Gp, unsigned char* Lp, int half, int kt) {
#pragma unroll
        for (int c = 0; c < 2; ++c)
            gload_lds16(Gp + (size_t)(half * 128 + c * 64 + srow) * K + kt + ssrc_col,
                        Lp + half * 16384 + c * 8192 + sdst);
    };

    f32x16 acc[4][2] = {};

    auto MF = [&](int m, int n, const i32x8& a, const i32x8& b) {
        acc[m][n] = __builtin_amdgcn_mfma_scale_f32_32x32x64_f8f6f4(
            a, b, acc[m][n],
            0, 0,                 // cbsz=fp8(e4m3), blgp=fp8(e4m3)
            0, 0x7F7F7F7F,        // A scale: 2^0
            0, 0x79797979);       // B scale: 2^-6 (undo w*2^6)
    };

    const int arb = wr * 128 + rl;   // A fragment base row
    const int brb = wc * 64 + rl;    // B fragment base row
    const int c00 = g2 * 32;         // ks=0 byte col
    const int c01 = 64 + g2 * 32;    // ks=1 byte col

    // ---- prologue: tile0 -> X (8 loads); Blo,Bhi(t1) -> Y.B (4 loads)
    stageh(Ag, XA, 0, 0);
    stageh(Ag, XA, 1, 0);
    stageh(Bg, XB, 0, 0);
    stageh(Bg, XB, 1, 0);
    stageh(Bg, YB, 0, BK);
    stageh(Bg, YB, 1, BK);
    asm volatile("s_waitcnt vmcnt(4)");  // tile0 landed; B(t1) in flight
    __builtin_amdgcn_s_barrier();

    for (int i = 0; i < NT / 2; ++i) {
        const int t0 = 2 * i;
        const int ktO = (t0 + 1) * BK;   // odd tile -> Y
        const int ktE = (t0 + 2) * BK;   // next even -> X
        const int ktO2 = (t0 + 3) * BK;  // next odd -> Y
        const bool pf = (t0 + 2 < NT);

        bf16x8_pad:;  // (label unused; keeps structure readable)
        i32x8 bf00, bf10, bf01, bf11, a0, a1;

        // P1: read ALL B frags + af[0,1]@ks0 from X; stage Alo(t0+1)->Y.A
        bf00 = frag32(XB, brb, c00);
        bf10 = frag32(XB, brb + 32, c00);
        bf01 = frag32(XB, brb, c01);
        bf11 = frag32(XB, brb + 32, c01);
        a0 = frag32(XA, arb, c00);
        a1 = frag32(XA, arb + 32, c00);
        stageh(Ag, YA, 0, ktO);
        __builtin_amdgcn_s_barrier();
        asm volatile("s_waitcnt lgkmcnt(0)");
        __builtin_amdgcn_s_setprio(1);
        MF(0, 0, a0, bf00); MF(0, 1, a0, bf10);
        MF(1, 0, a1, bf00); MF(1, 1, a1, bf10);
        __builtin_amdgcn_s_setprio(0);
        __builtin_amdgcn_s_barrier();

        // P2: read af[0,1]@ks1; stage Ahi(t0+1)->Y.A, Blo(t0+2)->X.B
        a0 = frag32(XA, arb, c01);
        a1 = frag32(XA, arb + 32, c01);
        stageh(Ag, YA, 1, ktO);
        if (pf) stageh(Bg, XB, 0, ktE);
        __builtin_amdgcn_s_barrier();
        asm volatile("s_waitcnt lgkmcnt(0)");
        __builtin_amdgcn_s_setprio(1);
        MF(0, 0, a0, bf01); MF(0, 1, a0, bf11);
        MF(1, 0, a1, bf01); MF(1, 1, a1, bf11);
        __builtin_amdgcn_s_setprio(0);
        __builtin_amdgcn_s_barrier();

        // P3: read af[2,3]@ks0; stage Bhi(t0+2)->X.B
        a0 = frag32(XA, arb + 64, c00);
        a1 = frag32(XA, arb + 96, c00);
        if (pf) stageh(Bg, XB, 1, ktE);
        __builtin_amdgcn_s_barrier();
        asm volatile("s_waitcnt lgkmcnt(0)");
        __builtin_amdgcn_s_setprio(1);
        MF(2, 0, a0, bf00); MF(2, 1, a0, bf10);
        MF(3, 0, a1, bf00); MF(3, 1, a1, bf10);
        __builtin_amdgcn_s_setprio(0);
        __builtin_amdgcn_s_barrier();

        // P4: read af[2,3]@ks1; counted wait: tile t0+1 landed (B(t0+2) stays)
        a0 = frag32(XA, arb + 64, c01);
        a1 = frag32(XA, arb + 96, c01);
        __builtin_amdgcn_s_barrier();
        asm volatile("s_waitcnt lgkmcnt(0)");
        __builtin_amdgcn_s_setprio(1);
        MF(2, 0, a0, bf01); MF(2, 1, a0, bf11);
        MF(3, 0, a1, bf01); MF(3, 1, a1, bf11);
        __builtin_amdgcn_s_setprio(0);
        if (pf) { asm volatile("s_waitcnt vmcnt(4)"); }
        else    { asm volatile("s_waitcnt vmcnt(0)"); }
        __builtin_amdgcn_s_barrier();

        // ---- tile t0+1 from Y ----
        // P5: read ALL B frags + af[0,1]@ks0 from Y; stage Alo(t0+2)->X.A
        bf00 = frag32(YB, brb, c00);
        bf10 = frag32(YB, brb + 32, c00);
        bf01 = frag32(YB, brb, c01);
        bf11 = frag32(YB, brb + 32, c01);
        a0 = frag32(YA, arb, c00);
        a1 = frag32(YA, arb + 32, c00);
        if (pf) stageh(Ag, XA, 0, ktE);
        __builtin_amdgcn_s_barrier();
        asm volatile("s_waitcnt lgkmcnt(0)");
        __builtin_amdgcn_s_setprio(1);
        MF(0, 0, a0, bf00); MF(0, 1, a0, bf10);
        MF(1, 0, a1, bf00); MF(1, 1, a1, bf10);
        __builtin_amdgcn_s_setprio(0);
        __builtin_amdgcn_s_barrier();

        // P6: read af[0,1]@ks1; stage Ahi(t0+2)->X.A, Blo(t0+3)->Y.B
        a0 = frag32(YA, arb, c01);
        a1 = frag32(YA, arb + 32, c01);
        if (pf) {
            stageh(Ag, XA, 1, ktE);
            stageh(Bg, YB, 0, ktO2);
        }
        __builtin_amdgcn_s_barrier();
        asm volatile("s_waitcnt lgkmcnt(0)");
        __builtin_amdgcn_s_setprio(1);
        MF(0, 0, a0, bf01); MF(0, 1, a0, bf11);
        MF(1, 0, a1, bf01); MF(1, 1, a1, bf11);
        __builtin_amdgcn_s_setprio(0);
        __builtin_amdgcn_s_barrier();

        // P7: read af[2,3]@ks0; stage Bhi(t0+3)->Y.B
        a0 = frag32(YA, arb + 64, c00);
        a1 = frag32(YA, arb + 96, c00);
        if (pf) stageh(Bg, YB, 1, ktO2);
        __builtin_amdgcn_s_barrier();
        asm volatile("s_waitcnt lgkmcnt(0)");
        __builtin_amdgcn_s_setprio(1);
        MF(2, 0, a0, bf00); MF(2, 1, a0, bf10);
        MF(3, 0, a1, bf00); MF(3, 1, a1, bf10);
        __builtin_amdgcn_s_setprio(0);
        __builtin_amdgcn_s_barrier();

        // P8: read af[2,3]@ks1; counted wait: tile t0+2 landed (B(t0+3) stays)
        a0 = frag32(YA, arb + 64, c01);
        a1 = frag32(YA, arb + 96, c01);
        __builtin_amdgcn_s_barrier();
        asm volatile("s_waitcnt lgkmcnt(0)");
        __builtin_amdgcn_s_setprio(1);
        MF(2, 0, a0, bf01); MF(2, 1, a0, bf11);
        MF(3, 0, a1, bf01); MF(3, 1, a1, bf11);
        __builtin_amdgcn_s_setprio(0);
        if (pf) { asm volatile("s_waitcnt vmcnt(4)"); }
        else    { asm volatile("s_waitcnt vmcnt(0)"); }
        __builtin_amdgcn_s_barrier();
    }

    // epilogue: 32x32 C/D: col = lane&31, row = (reg&3)+8*(reg>>2)+4*(lane>>5)
#pragma unroll
    for (int n = 0; n < 2; ++n) {
        int col = bcol0 + wc * 64 + n * 32 + rl;
        float bv = bias[col];
#pragma unroll
        for (int m = 0; m < 4; ++m) {
            int rowb = arow0 + wr * 128 + m * 32 + g2 * 4;
#pragma unroll
            for (int reg = 0; reg < 16; ++reg) {
                int row = rowb + (reg & 3) + 8 * (reg >> 2);
                C[(size_t)row * N + col] = acc[m][n][reg] + bv;
            }
        }
    }
}

extern "C" void kernel_launch(void* const* d_in, const int* in_sizes, int n_in,
                              void* d_out, int out_size, void* d_ws, size_t ws_size,
                              hipStream_t stream) {
    const float* x = (const float*)d_in[0];     // [M,K]
    const float* w = (const float*)d_in[1];     // [N,K]
    const float* bias = (const float*)d_in[2];  // [N]
    float* out = (float*)d_out;

    const int N = in_sizes[2];                 // 16384
    const int K = in_sizes[1] / N;             // 4096
    const int M = in_sizes[0] / K;             // 8192

    unsigned char* xq = (unsigned char*)d_ws;          // M*K = 33.5 MB
    unsigned char* wq = xq + (size_t)M * K;            // N*K = 67 MB

    int nx8 = M * K / 8;
    int nw8 = N * K / 8;
    quant8<<<(nx8 + 255) / 256, 256, 0, stream>>>(
        (const float4*)x, (int2*)xq, nx8, 1.0f);
    quant8<<<(nw8 + 255) / 256, 256, 0, stream>>>(
        (const float4*)w, (int2*)wq, nw8, 64.0f);

    hipFuncSetAttribute((const void*)gemm_fp8,
                        hipFuncAttributeMaxDynamicSharedMemorySize, 131072);

    int nwg = (M / BM) * (N / BN);  // 32*64 = 2048, %8==0
    gemm_fp8<<<nwg, 512, 131072, stream>>>(
        xq, wq, bias, out, M, N, K);
}

// Round 13
// 794.162 us; speedup vs baseline: 4.1008x; 4.1008x over previous
//
#include <hip/hip_runtime.h>
#include <hip/hip_bf16.h>

// FP8Linear: out = Xq @ Wq^T + bias. Reference quantize (scale=1) == RNE
// conversion to OCP e4m3fn; x stored as e4m3(x); w stored as e4m3(w*2^6)
// with MFMA B-scale 2^-6 (e8m0 0x79) so all |w|>=2^-12 quantize EXACTLY.
// GEMM R13: occupancy-first. Per-wave acc[2][2] (64 AGPR) -> wave fits in
// 128 unified regs -> 4 waves/SIMD -> 2 blocks/CU (TLP hides the lockstep
// stall R11 measured; R10-vs-R11 showed occupancy ~ as valuable as port
// traffic). 128x256 tile, 8 waves (2Mx4N, 64x64 out), BK=64, dbuf 48KB
// static LDS, DMA prefetch 1 tile ahead, ONE __syncthreads per tile.
// mfma_scale_f32_32x32x64_f8f6f4; XOR-swizzled LDS (pre-swizzled DMA src);
// XCD block swizzle. launch_bounds(512,2) = intentional 128-VGPR cap.

typedef int i32x4 __attribute__((ext_vector_type(4)));
typedef int i32x8 __attribute__((ext_vector_type(8)));
typedef float f32x16 __attribute__((ext_vector_type(16)));

#define BM 128
#define BN 256
#define BK 64

// clip to +-448, scale (1 or 64), RNE-encode 8 f32 -> 8 e4m3 bytes.
__global__ __launch_bounds__(256) void quant8(
    const float4* __restrict__ in, int2* __restrict__ out, int n8, float scale) {
    int i = blockIdx.x * blockDim.x + threadIdx.x;
    if (i >= n8) return;
    float4 a = in[i * 2];
    float4 b = in[i * 2 + 1];
    float c0 = fminf(fmaxf(a.x, -448.f), 448.f) * scale;
    float c1 = fminf(fmaxf(a.y, -448.f), 448.f) * scale;
    float c2 = fminf(fmaxf(a.z, -448.f), 448.f) * scale;
    float c3 = fminf(fmaxf(a.w, -448.f), 448.f) * scale;
    float c4 = fminf(fmaxf(b.x, -448.f), 448.f) * scale;
    float c5 = fminf(fmaxf(b.y, -448.f), 448.f) * scale;
    float c6 = fminf(fmaxf(b.z, -448.f), 448.f) * scale;
    float c7 = fminf(fmaxf(b.w, -448.f), 448.f) * scale;
    int lo = __builtin_amdgcn_cvt_pk_fp8_f32(c0, c1, 0, false);
    lo = __builtin_amdgcn_cvt_pk_fp8_f32(c2, c3, lo, true);
    int hi = __builtin_amdgcn_cvt_pk_fp8_f32(c4, c5, 0, false);
    hi = __builtin_amdgcn_cvt_pk_fp8_f32(c6, c7, hi, true);
    out[i] = make_int2(lo, hi);
}

__device__ __forceinline__ void gload_lds16(const void* g, void* l) {
    __builtin_amdgcn_global_load_lds(
        (const __attribute__((address_space(1))) void*)g,
        (__attribute__((address_space(3))) void*)l,
        16, 0, 0);
}

// 64B-row tiles. LDS[r][c] holds G[r][c ^ sw(r)], sw(r) = (r&3)<<4.
// Read one lane's 32-byte k-block (logical cols [c0, c0+32)) of `row`.
__device__ __forceinline__ i32x8 frag32(const unsigned char* base, int row, int c0) {
    const int sw = (row & 3) << 4;
    const unsigned char* p = base + row * 64;
    i32x4 lo = *(const i32x4*)(p + (c0 ^ sw));
    i32x4 hi = *(const i32x4*)(p + ((c0 + 16) ^ sw));
    i32x8 r;
    r[0] = lo[0]; r[1] = lo[1]; r[2] = lo[2]; r[3] = lo[3];
    r[4] = hi[0]; r[5] = hi[1]; r[6] = hi[2]; r[7] = hi[3];
    return r;
}

// A: Xq8 [M][K] e4m3, B: Wq8 [N][K] e4m3 (pre-scaled by 2^6), C: [M][N] f32
__global__ __launch_bounds__(512, 2) void gemm_fp8(
    const unsigned char* __restrict__ A, const unsigned char* __restrict__ B,
    const float* __restrict__ bias, float* __restrict__ C,
    int M, int N, int K) {
    // buf0: A [0,8K) B [8K,24K); buf1: A [24K,32K) B [32K,48K)
    __shared__ unsigned char lds[49152];

    const int tid = threadIdx.x;
    const int lane = tid & 63;
    const int wave = tid >> 6;
    const int wr = wave >> 2;   // 0..1 -> 64 A-rows each
    const int wc = wave & 3;    // 0..3 -> 64 B-cols each

    // XCD-aware bijective block swizzle (nwg % 8 == 0)
    const int nwg = gridDim.x;
    const int per = nwg >> 3;
    const int bid = blockIdx.x;
    const int wg = (bid & 7) * per + (bid >> 3);
    const int mtiles = M / BM;
    const int bm = wg % mtiles;
    const int bn = wg / mtiles;

    const int arow0 = bm * BM, bcol0 = bn * BN;
    const int NT = K / BK;  // 64

    const int rl = lane & 31;    // fragment row-within-32 (A row / B col)
    const int g2 = lane >> 5;    // k-half selector
    const int c0 = g2 * 32;      // logical byte col of this lane's 32B block

    const unsigned char* const Ag = A + (size_t)arow0 * K;
    const unsigned char* const Bg = B + (size_t)bcol0 * K;

    // staging (64B rows): thread t covers row t>>2, col16 t&3.
    // LDS dest linear (DMA constraint), global source pre-swizzled:
    const int srow = tid >> 2;                        // 0..127
    const int scol = ((tid & 3) << 4) ^ (((tid >> 2) & 3) << 4);
    const int sdst = tid * 16;

    auto stage = [&](unsigned char* Lp, int kt) {
        // A: 8KB = 1 instr/thread
        gload_lds16(Ag + (size_t)srow * K + kt + scol, Lp + sdst);
        // B: 16KB = 2 instr/thread
#pragma unroll
        for (int c = 0; c < 2; ++c)
            gload_lds16(Bg + (size_t)(c * 128 + srow) * K + kt + scol,
                        Lp + 8192 + c * 8192 + sdst);
    };

    f32x16 acc[2][2] = {};

    // ---- prologue: tile 0 -> buf0
    stage(lds, 0);
    __syncthreads();  // implicit vmcnt(0): tile 0 landed

    for (int t = 0; t < NT; ++t) {
        const int cur = t & 1;
        const unsigned char* Ab = lds + cur * 24576;
        const unsigned char* Bb = Ab + 8192;
        unsigned char* Anx = lds + (cur ^ 1) * 24576;

        // issue next tile's DMAs first: full tile of latency cover
        if (t + 1 < NT) stage(Anx, (t + 1) * BK);

        i32x8 bf0 = frag32(Bb, wc * 64 + rl, c0);
        i32x8 bf1 = frag32(Bb, wc * 64 + 32 + rl, c0);
        i32x8 af0 = frag32(Ab, wr * 64 + rl, c0);
        i32x8 af1 = frag32(Ab, wr * 64 + 32 + rl, c0);

        acc[0][0] = __builtin_amdgcn_mfma_scale_f32_32x32x64_f8f6f4(
            af0, bf0, acc[0][0], 0, 0, 0, 0x7F7F7F7F, 0, 0x79797979);
        acc[0][1] = __builtin_amdgcn_mfma_scale_f32_32x32x64_f8f6f4(
            af0, bf1, acc[0][1], 0, 0, 0, 0x7F7F7F7F, 0, 0x79797979);
        acc[1][0] = __builtin_amdgcn_mfma_scale_f32_32x32x64_f8f6f4(
            af1, bf0, acc[1][0], 0, 0, 0, 0x7F7F7F7F, 0, 0x79797979);
        acc[1][1] = __builtin_amdgcn_mfma_scale_f32_32x32x64_f8f6f4(
            af1, bf1, acc[1][1], 0, 0, 0, 0x7F7F7F7F, 0, 0x79797979);

        // one sync/tile: DMAs issued ~full tile ago have landed; publishes
        // the next buffer and protects the one just consumed.
        __syncthreads();
    }

    // epilogue: 32x32 C/D: col = lane&31, row = (reg&3)+8*(reg>>2)+4*(lane>>5)
#pragma unroll
    for (int n = 0; n < 2; ++n) {
        int col = bcol0 + wc * 64 + n * 32 + rl;
        float bv = bias[col];
#pragma unroll
        for (int m = 0; m < 2; ++m) {
            int rowb = arow0 + wr * 64 + m * 32 + g2 * 4;
#pragma unroll
            for (int reg = 0; reg < 16; ++reg) {
                int row = rowb + (reg & 3) + 8 * (reg >> 2);
                C[(size_t)row * N + col] = acc[m][n][reg] + bv;
            }
        }
    }
}

extern "C" void kernel_launch(void* const* d_in, const int* in_sizes, int n_in,
                              void* d_out, int out_size, void* d_ws, size_t ws_size,
                              hipStream_t stream) {
    const float* x = (const float*)d_in[0];     // [M,K]
    const float* w = (const float*)d_in[1];     // [N,K]
    const float* bias = (const float*)d_in[2];  // [N]
    float* out = (float*)d_out;

    const int N = in_sizes[2];                 // 16384
    const int K = in_sizes[1] / N;             // 4096
    const int M = in_sizes[0] / K;             // 8192

    unsigned char* xq = (unsigned char*)d_ws;          // M*K = 33.5 MB
    unsigned char* wq = xq + (size_t)M * K;            // N*K = 67 MB

    int nx8 = M * K / 8;
    int nw8 = N * K / 8;
    quant8<<<(nx8 + 255) / 256, 256, 0, stream>>>(
        (const float4*)x, (int2*)xq, nx8, 1.0f);
    quant8<<<(nw8 + 255) / 256, 256, 0, stream>>>(
        (const float4*)w, (int2*)wq, nw8, 64.0f);

    int nwg = (M / BM) * (N / BN);  // 64*64 = 4096, %8==0
    gemm_fp8<<<nwg, 512, 0, stream>>>(
        xq, wq, bias, out, M, N, K);
}